// Round 10
// baseline (230.025 us; speedup 1.0000x reference)
//
#include <hip/hip_runtime.h>

#define NN 100000
#define EE 1600000
#define DD 128
#define NBK 782                 // ceil(NN/128) buckets of 128 rows
#define CAP 2560                // fixed bucket capacity (λ=2048, +11σ slack)
#define BINCH 4096              // edges per bucket_bin block
#define BINGRID ((EE + BINCH - 1) / BINCH)   // 391 blocks

typedef unsigned int uint;
typedef unsigned short ushort;
typedef float f32x4 __attribute__((ext_vector_type(4)));
typedef short bf16x8 __attribute__((ext_vector_type(8)));

__device__ inline float bf_lo(uint u) { return __uint_as_float(u << 16); }
__device__ inline float bf_hi(uint u) { return __uint_as_float(u & 0xffff0000u); }
__device__ inline ushort f2bf(float f) {           // round-to-nearest-even
    uint b = __float_as_uint(f);
    return (ushort)((b + 0x7fffu + ((b >> 16) & 1u)) >> 16);
}

// ---------------------------------------------------------------------------
// prep_all: blocks 0..63 -> W1 frag-pack, 64..127 -> W2, 128.. -> cast x
// ---------------------------------------------------------------------------
__global__ __launch_bounds__(256) void prep_all(
    const float* __restrict__ x, const float* __restrict__ W1,
    const float* __restrict__ W2, ushort* __restrict__ hbf,
    ushort* __restrict__ w1p, ushort* __restrict__ w2p, int n4)
{
    int bid = blockIdx.x;
    int t = threadIdx.x;
    if (bid < 128) {
        const float* W = (bid < 64) ? W1 : W2;
        ushort* Wp = (bid < 64) ? w1p : w2p;
        int idx = (bid & 63) * 256 + t;         // 16384 total
        int j  = idx & 7;
        int l  = (idx >> 3) & 63;
        int ct = (idx >> 9) & 7;
        int kk = idx >> 12;
        int k = kk * 32 + (l >> 4) * 8 + j;
        int c = ct * 16 + (l & 15);
        Wp[idx] = f2bf(W[k * DD + c]);
    } else {
        int i = (bid - 128) * 256 + t;
        if (i >= n4) return;
        float4 v = reinterpret_cast<const float4*>(x)[i];
        ushort4 o;
        o.x = f2bf(v.x); o.y = f2bf(v.y); o.z = f2bf(v.z); o.w = f2bf(v.w);
        reinterpret_cast<ushort4*>(hbf)[i] = o;
    }
}

// ---------------------------------------------------------------------------
// bucket_bin: 1024 threads, 4096 edges/block. LDS hist by bucket, ONE global
// atomicAdd per touched bucket reserves a contiguous run, records written
// run-contiguous (single block per line -> L2 write-merge).
// ---------------------------------------------------------------------------
__global__ __launch_bounds__(1024) void bucket_bin(
    const int* __restrict__ src, const int* __restrict__ dst,
    const float* __restrict__ val, int* __restrict__ gcnt,
    uint2* __restrict__ brec, int E)
{
    __shared__ int h[1024];
    __shared__ int base[1024];
    int t = threadIdx.x;
    int lo = blockIdx.x * BINCH, hi = min(E, lo + BINCH);
    h[t] = 0;
    __syncthreads();
    for (int i = lo + t; i < hi; i += 1024) atomicAdd(&h[dst[i] >> 7], 1);
    __syncthreads();
    {
        int c = h[t];
        base[t] = c ? atomicAdd(&gcnt[t], c) : 0;
        h[t] = 0;                       // reuse as local rank counter
    }
    __syncthreads();
    for (int i = lo + t; i < hi; i += 1024) {
        int d = dst[i];
        int b = d >> 7;
        int r = atomicAdd(&h[b], 1);
        uint key = ((uint)(d & 127) << 17) | (uint)src[i];
        brec[(size_t)b * CAP + base[b] + r] = make_uint2(key, __float_as_uint(val[i]));
    }
}

// ---------------------------------------------------------------------------
// bucket_csr: one block per bucket; row hist+scan -> rowbeg/rowdeg, then
// write dst-sorted 4B records (src<<15 | bf16(val)[14:0]) within segment.
// ---------------------------------------------------------------------------
__global__ __launch_bounds__(256) void bucket_csr(
    const uint2* __restrict__ brec, const int* __restrict__ gcnt,
    uint* __restrict__ epk, int* __restrict__ rowbeg,
    ushort* __restrict__ rowdeg, int n)
{
    __shared__ int rh[128], rb[128], scn[128];
    int b = blockIdx.x;
    int t = threadIdx.x;
    int seg0 = b * CAP;
    int cnt = gcnt[b];
    int row0 = b * 128;
    if (t < 128) rh[t] = 0;
    __syncthreads();
    for (int i = t; i < cnt; i += 256)
        atomicAdd(&rh[brec[seg0 + i].x >> 17], 1);
    __syncthreads();
    if (t < 128) scn[t] = rh[t];
    __syncthreads();
    for (int off = 1; off < 128; off <<= 1) {
        int u = (t < 128 && t >= off) ? scn[t - off] : 0;
        __syncthreads();
        if (t < 128) scn[t] += u;
        __syncthreads();
    }
    if (t < 128) {
        rb[t] = scn[t] - rh[t];         // exclusive, bucket-local
        int row = row0 + t;
        if (row < n) { rowbeg[row] = seg0 + rb[t]; rowdeg[row] = (ushort)rh[t]; }
        rh[t] = 0;                      // reuse as tail counter
    }
    __syncthreads();
    for (int i = t; i < cnt; i += 256) {
        uint2 rec = brec[seg0 + i];
        uint r = rec.x >> 17;
        int p = atomicAdd(&rh[r], 1);
        // val in [0,1): round fp32->bf16, keep low 15 bits (sign always 0)
        uint vb = ((rec.y + 0x8000u) >> 16) & 0x7fffu;
        epk[seg0 + rb[r] + p] = ((rec.x & 0x1ffffu) << 15) | vb;
    }
}

// ---------------------------------------------------------------------------
// SpMM-CSR bf16 -> bf16, pair-edge gathers: wave splits into two 32-lane
// halves; each half gathers a DIFFERENT edge at 8B/lane (4 cols). Edge words
// are wave-uniform s_loads. Halves combine via shfl_xor(32) at the end.
// ---------------------------------------------------------------------------
__global__ __launch_bounds__(256) void spmm_bf(
    const ushort* __restrict__ H, const int* __restrict__ rowbeg,
    const ushort* __restrict__ rowdeg, const uint* __restrict__ epk,
    ushort* __restrict__ out, int n)
{
    int w = (blockIdx.x * 256 + threadIdx.x) >> 6;
    w = __builtin_amdgcn_readfirstlane(w);   // wave-uniform -> SGPR
    if (w >= n) return;
    const int lane = threadIdx.x & 63;
    const int li   = lane & 31;              // 4 cols per lane: 4*li..4*li+3
    const int half = lane >> 5;              // 0: even edges, 1: odd edges
    int beg = rowbeg[w];
    int deg = rowdeg[w];
    int end = beg + deg;
    float a0 = 0.f, a1 = 0.f, a2 = 0.f, a3 = 0.f;
    int e = beg;
    for (; e + 16 <= end; e += 16) {
        uint u[16];
#pragma unroll
        for (int k = 0; k < 16; ++k) u[k] = epk[e + k];
#pragma unroll
        for (int k = 0; k < 8; ++k) {
            uint ue = half ? u[2 * k + 1] : u[2 * k];
            uint2 hv = *reinterpret_cast<const uint2*>(
                &H[(size_t)(ue >> 15) * DD + li * 4]);
            float v = __uint_as_float((ue & 0x7fffu) << 16);
            a0 = fmaf(v, bf_lo(hv.x), a0);
            a1 = fmaf(v, bf_hi(hv.x), a1);
            a2 = fmaf(v, bf_lo(hv.y), a2);
            a3 = fmaf(v, bf_hi(hv.y), a3);
        }
    }
    for (; e + 2 <= end; e += 2) {
        uint u0 = epk[e], u1 = epk[e + 1];
        uint ue = half ? u1 : u0;
        uint2 hv = *reinterpret_cast<const uint2*>(
            &H[(size_t)(ue >> 15) * DD + li * 4]);
        float v = __uint_as_float((ue & 0x7fffu) << 16);
        a0 = fmaf(v, bf_lo(hv.x), a0);
        a1 = fmaf(v, bf_hi(hv.x), a1);
        a2 = fmaf(v, bf_lo(hv.y), a2);
        a3 = fmaf(v, bf_hi(hv.y), a3);
    }
    if (e < end) {
        uint u0 = epk[e];
        uint2 hv = *reinterpret_cast<const uint2*>(
            &H[(size_t)(u0 >> 15) * DD + li * 4]);
        float v = half ? 0.f : __uint_as_float((u0 & 0x7fffu) << 16);
        a0 = fmaf(v, bf_lo(hv.x), a0);
        a1 = fmaf(v, bf_hi(hv.x), a1);
        a2 = fmaf(v, bf_lo(hv.y), a2);
        a3 = fmaf(v, bf_hi(hv.y), a3);
    }
    a0 += __shfl_xor(a0, 32, 64);
    a1 += __shfl_xor(a1, 32, 64);
    a2 += __shfl_xor(a2, 32, 64);
    a3 += __shfl_xor(a3, 32, 64);
    if (half == 0) {
        uint2 o;
        o.x = ((uint)f2bf(a1) << 16) | (uint)f2bf(a0);
        o.y = ((uint)f2bf(a3) << 16) | (uint)f2bf(a2);
        *reinterpret_cast<uint2*>(&out[(size_t)w * DD + li * 4]) = o;
    }
}

// ---------------------------------------------------------------------------
// O = bf16(relu(A @ W + b))  via mfma_f32_16x16x32_bf16
// ---------------------------------------------------------------------------
__global__ __launch_bounds__(256) void linear_mfma_relu(
    const ushort* __restrict__ A, const ushort* __restrict__ Wp,
    const float* __restrict__ bias, ushort* __restrict__ O, int n)
{
    const int wv = threadIdx.x >> 6;
    const int l  = threadIdx.x & 63;
    const int row0 = blockIdx.x * 64 + wv * 16;
    const int m = l & 15, g = l >> 4;

    f32x4 acc[8];
#pragma unroll
    for (int ct = 0; ct < 8; ++ct) acc[ct] = (f32x4){0.f, 0.f, 0.f, 0.f};

#pragma unroll
    for (int kk = 0; kk < 4; ++kk) {
        bf16x8 a = *reinterpret_cast<const bf16x8*>(
            &A[(size_t)(row0 + m) * DD + kk * 32 + g * 8]);
#pragma unroll
        for (int ct = 0; ct < 8; ++ct) {
            bf16x8 b = *reinterpret_cast<const bf16x8*>(&Wp[((kk * 8 + ct) * 64 + l) * 8]);
            acc[ct] = __builtin_amdgcn_mfma_f32_16x16x32_bf16(a, b, acc[ct], 0, 0, 0);
        }
    }
#pragma unroll
    for (int ct = 0; ct < 8; ++ct) {
        int c = ct * 16 + m;
        float bb = bias[c];
#pragma unroll
        for (int r = 0; r < 4; ++r) {
            int row = row0 + g * 4 + r;
            if (row < n)
                O[(size_t)row * DD + c] = f2bf(fmaxf(acc[ct][r] + bb, 0.f));
        }
    }
}

// ---------------------------------------------------------------------------
// out[row] = relu(A @ W + b) . Wout + bout   (layer-2 linear + head, fused)
// ---------------------------------------------------------------------------
__global__ __launch_bounds__(256) void linear_mfma_dot(
    const ushort* __restrict__ A, const ushort* __restrict__ Wp,
    const float* __restrict__ bias, const float* __restrict__ Wout,
    const float* __restrict__ bout, float* __restrict__ out, int n)
{
    const int wv = threadIdx.x >> 6;
    const int l  = threadIdx.x & 63;
    const int row0 = blockIdx.x * 64 + wv * 16;
    const int m = l & 15, g = l >> 4;

    f32x4 acc[8];
#pragma unroll
    for (int ct = 0; ct < 8; ++ct) acc[ct] = (f32x4){0.f, 0.f, 0.f, 0.f};

#pragma unroll
    for (int kk = 0; kk < 4; ++kk) {
        bf16x8 a = *reinterpret_cast<const bf16x8*>(
            &A[(size_t)(row0 + m) * DD + kk * 32 + g * 8]);
#pragma unroll
        for (int ct = 0; ct < 8; ++ct) {
            bf16x8 b = *reinterpret_cast<const bf16x8*>(&Wp[((kk * 8 + ct) * 64 + l) * 8]);
            acc[ct] = __builtin_amdgcn_mfma_f32_16x16x32_bf16(a, b, acc[ct], 0, 0, 0);
        }
    }
    float srow[4] = {0.f, 0.f, 0.f, 0.f};
#pragma unroll
    for (int ct = 0; ct < 8; ++ct) {
        int c = ct * 16 + m;
        float bb = bias[c];
        float wo = Wout[c];
#pragma unroll
        for (int r = 0; r < 4; ++r)
            srow[r] = fmaf(fmaxf(acc[ct][r] + bb, 0.f), wo, srow[r]);
    }
#pragma unroll
    for (int r = 0; r < 4; ++r) {
        float s = srow[r];
        s += __shfl_xor(s, 1, 64);
        s += __shfl_xor(s, 2, 64);
        s += __shfl_xor(s, 4, 64);
        s += __shfl_xor(s, 8, 64);
        srow[r] = s;
    }
    if (m == 0) {
        float bo = bout[0];
#pragma unroll
        for (int r = 0; r < 4; ++r) {
            int row = row0 + g * 4 + r;
            if (row < n) out[row] = srow[r] + bo;
        }
    }
}

extern "C" void kernel_launch(void* const* d_in, const int* in_sizes, int n_in,
                              void* d_out, int out_size, void* d_ws, size_t ws_size,
                              hipStream_t stream)
{
    const float* x    = (const float*)d_in[0];
    const int*   esrc = (const int*)  d_in[1];
    const int*   edst = (const int*)  d_in[2];
    const float* eval = (const float*)d_in[3];
    const float* W1   = (const float*)d_in[4];
    const float* b1   = (const float*)d_in[5];
    const float* W2   = (const float*)d_in[6];
    const float* b2   = (const float*)d_in[7];
    const float* Wout = (const float*)d_in[8];
    const float* bout = (const float*)d_in[9];
    float* out = (float*)d_out;

    // workspace layout
    ushort* w1p    = (ushort*)d_ws;                      // 16384
    ushort* w2p    = w1p + 16384;                        // 16384
    ushort* hbf    = w2p + 16384;                        // [N][128] bf16 x
    ushort* bufS   = hbf + (size_t)NN * DD;              // [N][128] bf16 spmm out
    ushort* bufL   = bufS + (size_t)NN * DD;             // [N][128] bf16 layer-1 out
    uint*   epk    = (uint*)(bufL + (size_t)NN * DD);    // [NBK*CAP] packed records
    uint2*  brec   = (uint2*)(epk + (size_t)NBK * CAP);  // [NBK*CAP] bucket records
    int*    gcnt   = (int*)(brec + (size_t)NBK * CAP);   // [1024]
    int*    rowbeg = gcnt + 1024;                        // [N]
    ushort* rowdeg = (ushort*)(rowbeg + NN);             // [N]

    const int spmmGrid = (NN * 64 + 255) / 256;
    const int linGrid  = (NN + 63) / 64;
    const int castGrid = (NN * DD / 4 + 255) / 256;      // 12500

    // --- build dst-sorted edge structure (fixed-capacity bucket sort) ---
    hipMemsetAsync(gcnt, 0, 1024 * sizeof(int), stream);
    prep_all<<<castGrid + 128, 256, 0, stream>>>(x, W1, W2, hbf, w1p, w2p, NN * DD / 4);
    bucket_bin<<<BINGRID, 1024, 0, stream>>>(esrc, edst, eval, gcnt, brec, EE);
    bucket_csr<<<NBK, 256, 0, stream>>>(brec, gcnt, epk, rowbeg, rowdeg, NN);

    // --- layer 1 ---
    spmm_bf<<<spmmGrid, 256, 0, stream>>>(hbf, rowbeg, rowdeg, epk, bufS, NN);
    linear_mfma_relu<<<linGrid, 256, 0, stream>>>(bufS, w1p, b1, bufL, NN);
    // --- layer 2 ---
    spmm_bf<<<spmmGrid, 256, 0, stream>>>(bufL, rowbeg, rowdeg, epk, bufS, NN);
    linear_mfma_dot<<<linGrid, 256, 0, stream>>>(bufS, w2p, b2, Wout, bout, out, NN);
}

// Round 11
// 197.918 us; speedup vs baseline: 1.1622x; 1.1622x over previous
//
#include <hip/hip_runtime.h>

#define NN 100000
#define EE 1600000
#define DD 128
#define NBK 782                 // ceil(NN/128) buckets of 128 rows
#define CAP 2560                // fixed bucket capacity (λ=2048, +11σ slack)
#define BINCH 4096              // edges per bucket_bin block
#define BINGRID ((EE + BINCH - 1) / BINCH)   // 391 blocks

typedef unsigned int uint;
typedef unsigned short ushort;
typedef float f32x4 __attribute__((ext_vector_type(4)));
typedef short bf16x8 __attribute__((ext_vector_type(8)));

__device__ inline float bf_lo(uint u) { return __uint_as_float(u << 16); }
__device__ inline float bf_hi(uint u) { return __uint_as_float(u & 0xffff0000u); }
__device__ inline ushort f2bf(float f) {           // round-to-nearest-even
    uint b = __float_as_uint(f);
    return (ushort)((b + 0x7fffu + ((b >> 16) & 1u)) >> 16);
}

// ---------------------------------------------------------------------------
// prep_all: blocks 0..63 -> W1 frag-pack, 64..127 -> W2,
//           blocks 128..131 -> clear gcnt, 132.. -> cast x to bf16
// ---------------------------------------------------------------------------
__global__ __launch_bounds__(256) void prep_all(
    const float* __restrict__ x, const float* __restrict__ W1,
    const float* __restrict__ W2, ushort* __restrict__ hbf,
    ushort* __restrict__ w1p, ushort* __restrict__ w2p,
    int* __restrict__ gcnt, int n4)
{
    int bid = blockIdx.x;
    int t = threadIdx.x;
    if (bid < 128) {
        const float* W = (bid < 64) ? W1 : W2;
        ushort* Wp = (bid < 64) ? w1p : w2p;
        int idx = (bid & 63) * 256 + t;         // 16384 total
        int j  = idx & 7;
        int l  = (idx >> 3) & 63;
        int ct = (idx >> 9) & 7;
        int kk = idx >> 12;
        int k = kk * 32 + (l >> 4) * 8 + j;
        int c = ct * 16 + (l & 15);
        Wp[idx] = f2bf(W[k * DD + c]);
    } else if (bid < 132) {
        gcnt[(bid - 128) * 256 + t] = 0;
    } else {
        int i = (bid - 132) * 256 + t;
        if (i >= n4) return;
        float4 v = reinterpret_cast<const float4*>(x)[i];
        ushort4 o;
        o.x = f2bf(v.x); o.y = f2bf(v.y); o.z = f2bf(v.z); o.w = f2bf(v.w);
        reinterpret_cast<ushort4*>(hbf)[i] = o;
    }
}

// ---------------------------------------------------------------------------
// bucket_bin: 1024 threads, 4096 edges/block. LDS hist by bucket, ONE global
// atomicAdd per touched bucket reserves a contiguous run, records written
// run-contiguous (single block per line -> L2 write-merge).
// ---------------------------------------------------------------------------
__global__ __launch_bounds__(1024) void bucket_bin(
    const int* __restrict__ src, const int* __restrict__ dst,
    const float* __restrict__ val, int* __restrict__ gcnt,
    uint2* __restrict__ brec, int E)
{
    __shared__ int h[1024];
    __shared__ int base[1024];
    int t = threadIdx.x;
    int lo = blockIdx.x * BINCH, hi = min(E, lo + BINCH);
    h[t] = 0;
    __syncthreads();
    for (int i = lo + t; i < hi; i += 1024) atomicAdd(&h[dst[i] >> 7], 1);
    __syncthreads();
    {
        int c = h[t];
        base[t] = c ? atomicAdd(&gcnt[t], c) : 0;
        h[t] = 0;                       // reuse as local rank counter
    }
    __syncthreads();
    for (int i = lo + t; i < hi; i += 1024) {
        int d = dst[i];
        int b = d >> 7;
        int r = atomicAdd(&h[b], 1);
        uint key = ((uint)(d & 127) << 17) | (uint)src[i];
        brec[(size_t)b * CAP + base[b] + r] = make_uint2(key, __float_as_uint(val[i]));
    }
}

// ---------------------------------------------------------------------------
// bucket_csr: one block per bucket; row hist+scan -> rowbeg/rowdeg, then
// write dst-sorted 4B records (src<<15 | bf16(val)[14:0]) within segment.
// ---------------------------------------------------------------------------
__global__ __launch_bounds__(256) void bucket_csr(
    const uint2* __restrict__ brec, const int* __restrict__ gcnt,
    uint* __restrict__ epk, int* __restrict__ rowbeg,
    ushort* __restrict__ rowdeg, int n)
{
    __shared__ int rh[128], rb[128], scn[128];
    int b = blockIdx.x;
    int t = threadIdx.x;
    int seg0 = b * CAP;
    int cnt = gcnt[b];
    int row0 = b * 128;
    if (t < 128) rh[t] = 0;
    __syncthreads();
    for (int i = t; i < cnt; i += 256)
        atomicAdd(&rh[brec[seg0 + i].x >> 17], 1);
    __syncthreads();
    if (t < 128) scn[t] = rh[t];
    __syncthreads();
    for (int off = 1; off < 128; off <<= 1) {
        int u = (t < 128 && t >= off) ? scn[t - off] : 0;
        __syncthreads();
        if (t < 128) scn[t] += u;
        __syncthreads();
    }
    if (t < 128) {
        rb[t] = scn[t] - rh[t];         // exclusive, bucket-local
        int row = row0 + t;
        if (row < n) { rowbeg[row] = seg0 + rb[t]; rowdeg[row] = (ushort)rh[t]; }
        rh[t] = 0;                      // reuse as tail counter
    }
    __syncthreads();
    for (int i = t; i < cnt; i += 256) {
        uint2 rec = brec[seg0 + i];
        uint r = rec.x >> 17;
        int p = atomicAdd(&rh[r], 1);
        // val in [0,1): round fp32->bf16, keep low 15 bits (sign always 0)
        uint vb = ((rec.y + 0x8000u) >> 16) & 0x7fffu;
        epk[seg0 + rb[r] + p] = ((rec.x & 0x1ffffu) << 15) | vb;
    }
}

// ---------------------------------------------------------------------------
// SpMM-CSR bf16 -> bf16: out[i,:] = sum val * H[src,:]  (fp32 accum)
// one wave per row; wave-uniform scalar loads for the edge stream (s_load),
// vector gathers only for H rows; unroll-8 with NAMED registers (no arrays).
// ---------------------------------------------------------------------------
__global__ __launch_bounds__(256) void spmm_bf(
    const ushort* __restrict__ H, const int* __restrict__ rowbeg,
    const ushort* __restrict__ rowdeg, const uint* __restrict__ epk,
    ushort* __restrict__ out, int n)
{
    int w = (blockIdx.x * 256 + threadIdx.x) >> 6;
    w = __builtin_amdgcn_readfirstlane(w);   // wave-uniform -> SGPR
    if (w >= n) return;
    int lane = threadIdx.x & 63;
    int beg = rowbeg[w];
    int deg = rowdeg[w];
    int end = beg + deg;
    float accx = 0.f, accy = 0.f;
    int e = beg;
    for (; e + 8 <= end; e += 8) {
        uint u0 = epk[e + 0], u1 = epk[e + 1], u2 = epk[e + 2], u3 = epk[e + 3];
        uint u4 = epk[e + 4], u5 = epk[e + 5], u6 = epk[e + 6], u7 = epk[e + 7];
        uint h0 = *reinterpret_cast<const uint*>(&H[(size_t)(u0 >> 15) * DD + lane * 2]);
        uint h1 = *reinterpret_cast<const uint*>(&H[(size_t)(u1 >> 15) * DD + lane * 2]);
        uint h2 = *reinterpret_cast<const uint*>(&H[(size_t)(u2 >> 15) * DD + lane * 2]);
        uint h3 = *reinterpret_cast<const uint*>(&H[(size_t)(u3 >> 15) * DD + lane * 2]);
        uint h4 = *reinterpret_cast<const uint*>(&H[(size_t)(u4 >> 15) * DD + lane * 2]);
        uint h5 = *reinterpret_cast<const uint*>(&H[(size_t)(u5 >> 15) * DD + lane * 2]);
        uint h6 = *reinterpret_cast<const uint*>(&H[(size_t)(u6 >> 15) * DD + lane * 2]);
        uint h7 = *reinterpret_cast<const uint*>(&H[(size_t)(u7 >> 15) * DD + lane * 2]);
        float v0 = __uint_as_float((u0 & 0x7fffu) << 16);
        float v1 = __uint_as_float((u1 & 0x7fffu) << 16);
        float v2 = __uint_as_float((u2 & 0x7fffu) << 16);
        float v3 = __uint_as_float((u3 & 0x7fffu) << 16);
        float v4 = __uint_as_float((u4 & 0x7fffu) << 16);
        float v5 = __uint_as_float((u5 & 0x7fffu) << 16);
        float v6 = __uint_as_float((u6 & 0x7fffu) << 16);
        float v7 = __uint_as_float((u7 & 0x7fffu) << 16);
        accx = fmaf(v0, bf_lo(h0), accx); accy = fmaf(v0, bf_hi(h0), accy);
        accx = fmaf(v1, bf_lo(h1), accx); accy = fmaf(v1, bf_hi(h1), accy);
        accx = fmaf(v2, bf_lo(h2), accx); accy = fmaf(v2, bf_hi(h2), accy);
        accx = fmaf(v3, bf_lo(h3), accx); accy = fmaf(v3, bf_hi(h3), accy);
        accx = fmaf(v4, bf_lo(h4), accx); accy = fmaf(v4, bf_hi(h4), accy);
        accx = fmaf(v5, bf_lo(h5), accx); accy = fmaf(v5, bf_hi(h5), accy);
        accx = fmaf(v6, bf_lo(h6), accx); accy = fmaf(v6, bf_hi(h6), accy);
        accx = fmaf(v7, bf_lo(h7), accx); accy = fmaf(v7, bf_hi(h7), accy);
    }
    for (; e + 2 <= end; e += 2) {
        uint u0 = epk[e + 0], u1 = epk[e + 1];
        uint h0 = *reinterpret_cast<const uint*>(&H[(size_t)(u0 >> 15) * DD + lane * 2]);
        uint h1 = *reinterpret_cast<const uint*>(&H[(size_t)(u1 >> 15) * DD + lane * 2]);
        float v0 = __uint_as_float((u0 & 0x7fffu) << 16);
        float v1 = __uint_as_float((u1 & 0x7fffu) << 16);
        accx = fmaf(v0, bf_lo(h0), accx); accy = fmaf(v0, bf_hi(h0), accy);
        accx = fmaf(v1, bf_lo(h1), accx); accy = fmaf(v1, bf_hi(h1), accy);
    }
    if (e < end) {
        uint u0 = epk[e];
        uint h0 = *reinterpret_cast<const uint*>(&H[(size_t)(u0 >> 15) * DD + lane * 2]);
        float v0 = __uint_as_float((u0 & 0x7fffu) << 16);
        accx = fmaf(v0, bf_lo(h0), accx); accy = fmaf(v0, bf_hi(h0), accy);
    }
    uint o = ((uint)f2bf(accy) << 16) | (uint)f2bf(accx);
    *reinterpret_cast<uint*>(&out[(size_t)w * DD + lane * 2]) = o;
}

// ---------------------------------------------------------------------------
// O = bf16(relu(A @ W + b))  via mfma_f32_16x16x32_bf16
// ---------------------------------------------------------------------------
__global__ __launch_bounds__(256) void linear_mfma_relu(
    const ushort* __restrict__ A, const ushort* __restrict__ Wp,
    const float* __restrict__ bias, ushort* __restrict__ O, int n)
{
    const int wv = threadIdx.x >> 6;
    const int l  = threadIdx.x & 63;
    const int row0 = blockIdx.x * 64 + wv * 16;
    const int m = l & 15, g = l >> 4;

    f32x4 acc[8];
#pragma unroll
    for (int ct = 0; ct < 8; ++ct) acc[ct] = (f32x4){0.f, 0.f, 0.f, 0.f};

#pragma unroll
    for (int kk = 0; kk < 4; ++kk) {
        bf16x8 a = *reinterpret_cast<const bf16x8*>(
            &A[(size_t)(row0 + m) * DD + kk * 32 + g * 8]);
#pragma unroll
        for (int ct = 0; ct < 8; ++ct) {
            bf16x8 b = *reinterpret_cast<const bf16x8*>(&Wp[((kk * 8 + ct) * 64 + l) * 8]);
            acc[ct] = __builtin_amdgcn_mfma_f32_16x16x32_bf16(a, b, acc[ct], 0, 0, 0);
        }
    }
#pragma unroll
    for (int ct = 0; ct < 8; ++ct) {
        int c = ct * 16 + m;
        float bb = bias[c];
#pragma unroll
        for (int r = 0; r < 4; ++r) {
            int row = row0 + g * 4 + r;
            if (row < n)
                O[(size_t)row * DD + c] = f2bf(fmaxf(acc[ct][r] + bb, 0.f));
        }
    }
}

// ---------------------------------------------------------------------------
// out[row] = relu(A @ W + b) . Wout + bout   (layer-2 linear + head, fused)
// ---------------------------------------------------------------------------
__global__ __launch_bounds__(256) void linear_mfma_dot(
    const ushort* __restrict__ A, const ushort* __restrict__ Wp,
    const float* __restrict__ bias, const float* __restrict__ Wout,
    const float* __restrict__ bout, float* __restrict__ out, int n)
{
    const int wv = threadIdx.x >> 6;
    const int l  = threadIdx.x & 63;
    const int row0 = blockIdx.x * 64 + wv * 16;
    const int m = l & 15, g = l >> 4;

    f32x4 acc[8];
#pragma unroll
    for (int ct = 0; ct < 8; ++ct) acc[ct] = (f32x4){0.f, 0.f, 0.f, 0.f};

#pragma unroll
    for (int kk = 0; kk < 4; ++kk) {
        bf16x8 a = *reinterpret_cast<const bf16x8*>(
            &A[(size_t)(row0 + m) * DD + kk * 32 + g * 8]);
#pragma unroll
        for (int ct = 0; ct < 8; ++ct) {
            bf16x8 b = *reinterpret_cast<const bf16x8*>(&Wp[((kk * 8 + ct) * 64 + l) * 8]);
            acc[ct] = __builtin_amdgcn_mfma_f32_16x16x32_bf16(a, b, acc[ct], 0, 0, 0);
        }
    }
    float srow[4] = {0.f, 0.f, 0.f, 0.f};
#pragma unroll
    for (int ct = 0; ct < 8; ++ct) {
        int c = ct * 16 + m;
        float bb = bias[c];
        float wo = Wout[c];
#pragma unroll
        for (int r = 0; r < 4; ++r)
            srow[r] = fmaf(fmaxf(acc[ct][r] + bb, 0.f), wo, srow[r]);
    }
#pragma unroll
    for (int r = 0; r < 4; ++r) {
        float s = srow[r];
        s += __shfl_xor(s, 1, 64);
        s += __shfl_xor(s, 2, 64);
        s += __shfl_xor(s, 4, 64);
        s += __shfl_xor(s, 8, 64);
        srow[r] = s;
    }
    if (m == 0) {
        float bo = bout[0];
#pragma unroll
        for (int r = 0; r < 4; ++r) {
            int row = row0 + g * 4 + r;
            if (row < n) out[row] = srow[r] + bo;
        }
    }
}

extern "C" void kernel_launch(void* const* d_in, const int* in_sizes, int n_in,
                              void* d_out, int out_size, void* d_ws, size_t ws_size,
                              hipStream_t stream)
{
    const float* x    = (const float*)d_in[0];
    const int*   esrc = (const int*)  d_in[1];
    const int*   edst = (const int*)  d_in[2];
    const float* eval = (const float*)d_in[3];
    const float* W1   = (const float*)d_in[4];
    const float* b1   = (const float*)d_in[5];
    const float* W2   = (const float*)d_in[6];
    const float* b2   = (const float*)d_in[7];
    const float* Wout = (const float*)d_in[8];
    const float* bout = (const float*)d_in[9];
    float* out = (float*)d_out;

    // workspace layout
    ushort* w1p    = (ushort*)d_ws;                      // 16384
    ushort* w2p    = w1p + 16384;                        // 16384
    ushort* hbf    = w2p + 16384;                        // [N][128] bf16 x
    ushort* bufS   = hbf + (size_t)NN * DD;              // [N][128] bf16 spmm out
    ushort* bufL   = bufS + (size_t)NN * DD;             // [N][128] bf16 layer-1 out
    uint*   epk    = (uint*)(bufL + (size_t)NN * DD);    // [NBK*CAP] packed records
    uint2*  brec   = (uint2*)(epk + (size_t)NBK * CAP);  // [NBK*CAP] bucket records
    int*    gcnt   = (int*)(brec + (size_t)NBK * CAP);   // [1024]
    int*    rowbeg = gcnt + 1024;                        // [N]
    ushort* rowdeg = (ushort*)(rowbeg + NN);             // [N]

    const int spmmGrid = (NN * 64 + 255) / 256;
    const int linGrid  = (NN + 63) / 64;
    const int castGrid = (NN * DD / 4 + 255) / 256;      // 12500

    // --- prep (W frag-pack + gcnt clear + x cast) and bucket sort ---
    prep_all<<<castGrid + 132, 256, 0, stream>>>(x, W1, W2, hbf, w1p, w2p, gcnt, NN * DD / 4);
    bucket_bin<<<BINGRID, 1024, 0, stream>>>(esrc, edst, eval, gcnt, brec, EE);
    bucket_csr<<<NBK, 256, 0, stream>>>(brec, gcnt, epk, rowbeg, rowdeg, NN);

    // --- layer 1 ---
    spmm_bf<<<spmmGrid, 256, 0, stream>>>(hbf, rowbeg, rowdeg, epk, bufS, NN);
    linear_mfma_relu<<<linGrid, 256, 0, stream>>>(bufS, w1p, b1, bufL, NN);
    // --- layer 2 ---
    spmm_bf<<<spmmGrid, 256, 0, stream>>>(bufL, rowbeg, rowdeg, epk, bufS, NN);
    linear_mfma_dot<<<linGrid, 256, 0, stream>>>(bufS, w2p, b2, Wout, bout, out, NN);
}